// Round 16
// baseline (2910.653 us; speedup 1.0000x reference)
//
#include <hip/hip_runtime.h>
#include <hip/hip_bf16.h>
#include <cmath>

// Problem constants (fixed by setup_inputs)
#define B    2048
#define NH   512
#define NC   316
#define TPC  317
#define ROWLEN (NC * TPC)   // 100172

// d_out layout (flat float32, return-order concat)
#define OFF_LOSS    ((size_t)0)
#define OFF_TGT     ((size_t)1)
#define OFF_TOPP    ((size_t)(1 + B))
#define OFF_BOTP    (OFF_TOPP + (size_t)B * NC)
#define OFF_TIDX    (OFF_BOTP + (size_t)B * TPC)
#define OFF_BIDX    (OFF_TIDX + (size_t)B)
#define OFF_RIDX    (OFF_BIDX + (size_t)B)
#define OFF_PREDS   (OFF_RIDX + (size_t)B)

// DIAGNOSTIC ROUND: k_gemms amplified x24 (idempotent reps). Warm reps are
// L3-resident (Wb 205MB < 256MB) -> separates cold-miss exposure (H1) from
// internal serialization cost (H2). True warm cost C = (dur - 95us)/23.
#define K1_SB 8
#define NTOPB (B / K1_SB)     // 256
#define KCH     4
#define KLEN    (NH / KCH)    // 128
#define SG      16
#define SCR_PAD 320

__global__ __launch_bounds__(320) void k_gemms(const float* __restrict__ X,
                                               const int* __restrict__ labels,
                                               const float* __restrict__ Wt,
                                               const float* __restrict__ bt,
                                               const float* __restrict__ Wb,
                                               float* __restrict__ scratch,
                                               float* __restrict__ out,
                                               int rep) {
    __shared__ float lg[K1_SB][NC];     // top branch (~10 KB)
    __shared__ int   list[B + SG];      // blogits branch (~8.3 KB)
    __shared__ int   cnt;
    const int tid = threadIdx.x;

    for (int r_ = 0; r_ < rep; ++r_) {
    if (blockIdx.x < NTOPB) {
        // ----------------- k_top v3 body -----------------
        const int b0 = blockIdx.x * K1_SB;

        if (tid < NC) {
            float acc[K1_SB];
            #pragma unroll
            for (int s = 0; s < K1_SB; ++s) acc[s] = 0.f;
            const float* __restrict__ Xb = X + (size_t)b0 * NH;
            #pragma unroll 2
            for (int k = 0; k < NH; k += 4) {
                const float w0 = Wt[(k + 0) * NC + tid];
                const float w1 = Wt[(k + 1) * NC + tid];
                const float w2 = Wt[(k + 2) * NC + tid];
                const float w3 = Wt[(k + 3) * NC + tid];
                #pragma unroll
                for (int s = 0; s < K1_SB; ++s) {
                    const float4 xv = *(const float4*)&Xb[s * NH + k];  // uniform -> s_load
                    acc[s] += xv.x * w0 + xv.y * w1 + xv.z * w2 + xv.w * w3;
                }
            }
            const float bbv = bt[tid];
            #pragma unroll
            for (int s = 0; s < K1_SB; ++s) lg[s][tid] = acc[s] + bbv;
        }
        __syncthreads();

        const int wave = tid >> 6, lane = tid & 63;
        float* __restrict__ top_probs = out + OFF_TOPP;
        float* __restrict__ top_indx  = out + OFF_TIDX;

        for (int s = wave; s < K1_SB; s += 5) {
            const int b = b0 + s;
            float m = -INFINITY; int mi = 0;
            for (int c = lane; c < NC; c += 64) {
                float v = lg[s][c];
                if (v > m) { m = v; mi = c; }
            }
            for (int off = 32; off > 0; off >>= 1) {
                float om = __shfl_xor(m, off);
                int omi  = __shfl_xor(mi, off);
                if (om > m || (om == m && omi < mi)) { m = om; mi = omi; }
            }
            float sum = 0.f;
            for (int c = lane; c < NC; c += 64) sum += expf(lg[s][c] - m);
            for (int off = 32; off > 0; off >>= 1) sum += __shfl_xor(sum, off);
            const float inv = 1.0f / sum;
            for (int c = lane; c < NC; c += 64)
                top_probs[(size_t)b * NC + c] = expf(lg[s][c] - m) * inv;
            if (lane == 0) top_indx[b] = (float)mi;
        }
        __syncthreads();
    } else {
        // ----------------- k_blogits body (KCH=4, nt weight loads) -----------------
        const int idx = blockIdx.x - NTOPB;
        const int c   = idx % NC;
        const int kc  = idx / NC;

        if (tid == 0) cnt = 0;
        __syncthreads();

        for (int i = tid; i < B; i += 320) {
            int lab = labels[i];
            if (lab / TPC == c) list[atomicAdd(&cnt, 1)] = i;
        }
        __syncthreads();
        const int n = cnt;
        if (n > 0) {
            if (tid < SG) list[n + tid] = list[0];   // pad: safe garbage samples
            __syncthreads();

            const float* __restrict__ Wc = Wb + (size_t)c * NH * TPC + (size_t)kc * KLEN * TPC;
            const int xoff = kc * KLEN;

            for (int start = 0; start < n; start += SG) {
                const int ns = min(SG, n - start);
                int sb[SG];
                #pragma unroll
                for (int s = 0; s < SG; ++s)
                    sb[s] = __builtin_amdgcn_readfirstlane(list[start + s]) * NH + xoff;

                if (tid < TPC) {
                    float acc[SG];
                    #pragma unroll
                    for (int s = 0; s < SG; ++s) acc[s] = 0.f;

                    for (int k = 0; k < KLEN; k += 4) {
                        const float w0 = __builtin_nontemporal_load(&Wc[(size_t)(k + 0) * TPC + tid]);
                        const float w1 = __builtin_nontemporal_load(&Wc[(size_t)(k + 1) * TPC + tid]);
                        const float w2 = __builtin_nontemporal_load(&Wc[(size_t)(k + 2) * TPC + tid]);
                        const float w3 = __builtin_nontemporal_load(&Wc[(size_t)(k + 3) * TPC + tid]);
                        #pragma unroll
                        for (int s = 0; s < 8; ++s) {
                            const float4 xv = *(const float4*)&X[sb[s] + k];   // s_load
                            acc[s] += xv.x * w0 + xv.y * w1 + xv.z * w2 + xv.w * w3;
                        }
                        #pragma unroll
                        for (int s = 8; s < SG; ++s) {
                            const float4 xv = *(const float4*)&X[sb[s] + k];   // s_load
                            acc[s] += xv.x * w0 + xv.y * w1 + xv.z * w2 + xv.w * w3;
                        }
                    }
                    for (int s = 0; s < ns; ++s)
                        scratch[((size_t)list[start + s] * KCH + kc) * SCR_PAD + tid] = acc[s];
                }
            }
        }
        __syncthreads();
    }
    asm volatile("" ::: "memory");
    }
}

// ------------- k_bfinal: reduce partials + bias, softmax, outputs -------------
__global__ __launch_bounds__(256) void k_bfinal(const int* __restrict__ labels,
                                                const float* __restrict__ bbias,
                                                const float* __restrict__ scratch,
                                                float* __restrict__ out) {
    const int tid  = threadIdx.x;
    const int lane = tid & 63;
    const int b    = blockIdx.x * 4 + (tid >> 6);

    const int lab = labels[b];
    const int c   = lab / TPC;
    const int pb  = lab - c * TPC;

    float lgv[5];
    #pragma unroll
    for (int i = 0; i < 5; ++i) {
        const int t = lane + 64 * i;
        float v = -INFINITY;
        if (t < TPC) {
            v = bbias[(size_t)c * TPC + t];
            #pragma unroll
            for (int kc = 0; kc < KCH; ++kc)
                v += scratch[((size_t)b * KCH + kc) * SCR_PAD + t];
        }
        lgv[i] = v;
    }

    float m = -INFINITY; int mi = 0;
    #pragma unroll
    for (int i = 0; i < 5; ++i) {
        const int t = lane + 64 * i;
        if (lgv[i] > m) { m = lgv[i]; mi = t; }
    }
    for (int off = 32; off > 0; off >>= 1) {
        float om = __shfl_xor(m, off);
        int omi  = __shfl_xor(mi, off);
        if (om > m || (om == m && omi < mi)) { m = om; mi = omi; }
    }

    float pv[5];
    float sum = 0.f;
    #pragma unroll
    for (int i = 0; i < 5; ++i) {
        const int t = lane + 64 * i;
        pv[i] = (t < TPC) ? expf(lgv[i] - m) : 0.f;
        sum += pv[i];
    }
    for (int off = 32; off > 0; off >>= 1) sum += __shfl_xor(sum, off);
    const float inv = 1.0f / sum;

    float* __restrict__ bot = out + OFF_BOTP + (size_t)b * TPC;
    float tsel = 0.f;
    #pragma unroll
    for (int i = 0; i < 5; ++i) {
        const int t = lane + 64 * i;
        if (t < TPC) {
            const float p = pv[i] * inv;
            bot[t] = p;
            if (t == pb) tsel = p;
        }
    }
    for (int off = 32; off > 0; off >>= 1) tsel += __shfl_xor(tsel, off);

    if (lane == 0) {
        out[OFF_TGT + b]  = out[OFF_TOPP + (size_t)b * NC + c] * tsel;
        out[OFF_BIDX + b] = (float)mi;
        out[OFF_RIDX + b] = out[OFF_TIDX + b] * (float)TPC + (float)mi;
    }
}

// ------------- k_preds v1 (accepted): 20 blocks/row scalar stream -------------
#define K3_THREADS 256
#define K3_ITERS   20
#define K3_BLOCKS_PER_ROW ((ROWLEN + K3_THREADS * K3_ITERS - 1) / (K3_THREADS * K3_ITERS))  // 20

__global__ __launch_bounds__(K3_THREADS) void k_preds(const float* __restrict__ out_ro,
                                                      float* __restrict__ preds) {
    __shared__ float tp[NC];
    __shared__ float bp[TPC];
    const int b = blockIdx.y;
    const int tid = threadIdx.x;

    const float* __restrict__ trow = out_ro + OFF_TOPP + (size_t)b * NC;
    const float* __restrict__ brow = out_ro + OFF_BOTP + (size_t)b * TPC;
    for (int i = tid; i < NC;  i += K3_THREADS) tp[i] = trow[i];
    for (int i = tid; i < TPC; i += K3_THREADS) bp[i] = brow[i];
    __syncthreads();

    int j = blockIdx.x * (K3_THREADS * K3_ITERS) + tid;
    int c = j / TPC;            // constant divisor -> magic-mul
    int t = j - c * TPC;
    float* __restrict__ row = preds + (size_t)b * ROWLEN;

    #pragma unroll
    for (int i = 0; i < K3_ITERS; ++i) {
        if (j < ROWLEN) row[j] = tp[c] * bp[t];
        j += K3_THREADS;
        t += K3_THREADS;
        if (t >= TPC) { t -= TPC; c++; }
    }
}

// ------------- k_loss: deterministic single-block reduce -------------
__global__ __launch_bounds__(256) void k_loss(const float* __restrict__ out_ro,
                                              float* __restrict__ out) {
    __shared__ float red[4];
    const int tid = threadIdx.x;
    const float* __restrict__ target = out_ro + OFF_TGT;
    float s = 0.f;
    for (int i = tid; i < B; i += 256) s += logf(target[i]);
    for (int off = 32; off > 0; off >>= 1) s += __shfl_xor(s, off);
    if ((tid & 63) == 0) red[tid >> 6] = s;
    __syncthreads();
    if (tid == 0) {
        float tot = red[0] + red[1] + red[2] + red[3];
        out[OFF_LOSS] = -tot / (float)B;
    }
}

extern "C" void kernel_launch(void* const* d_in, const int* in_sizes, int n_in,
                              void* d_out, int out_size, void* d_ws, size_t ws_size,
                              hipStream_t stream) {
    const float* X      = (const float*)d_in[0];
    const int*   labels = (const int*)d_in[1];
    // d_in[2] = ntokens_per_class (scalar, hardcoded as TPC)
    const float* Wt = (const float*)d_in[3];
    const float* bt = (const float*)d_in[4];
    const float* Wb = (const float*)d_in[5];
    const float* bb = (const float*)d_in[6];
    float* out = (float*)d_out;
    float* scratch = out + OFF_PREDS;   // preds region doubles as scratch,
                                        // fully overwritten by k_preds later

    // DIAGNOSTIC: gemms amplified x24 — true warm cost C = (dur-95us)/23.
    k_gemms<<<dim3(NTOPB + NC * KCH), dim3(320), 0, stream>>>(X, labels, Wt, bt, Wb, scratch, out, 24);
    k_bfinal<<<dim3(B / 4), dim3(256), 0, stream>>>(labels, bb, scratch, out);
    k_preds<<<dim3(K3_BLOCKS_PER_ROW, B), dim3(K3_THREADS), 0, stream>>>(out, out + OFF_PREDS);
    k_loss<<<dim3(1), dim3(256), 0, stream>>>(out, out);
}

// Round 17
// 314.470 us; speedup vs baseline: 9.2557x; 9.2557x over previous
//
#include <hip/hip_runtime.h>
#include <hip/hip_bf16.h>
#include <cmath>

// Problem constants (fixed by setup_inputs)
#define B    2048
#define NH   512
#define NC   316
#define TPC  317
#define ROWLEN (NC * TPC)   // 100172

// d_out layout (flat float32, return-order concat)
#define OFF_LOSS    ((size_t)0)
#define OFF_TGT     ((size_t)1)
#define OFF_TOPP    ((size_t)(1 + B))
#define OFF_BOTP    (OFF_TOPP + (size_t)B * NC)
#define OFF_TIDX    (OFF_BOTP + (size_t)B * TPC)
#define OFF_BIDX    (OFF_TIDX + (size_t)B)
#define OFF_RIDX    (OFF_BIDX + (size_t)B)
#define OFF_PREDS   (OFF_RIDX + (size_t)B)

// ---- fused GEMM kernel ----
// R16 diagnostic: warm reps ~= cold (H2: latency-structure-bound, not HBM),
// OccupancyPercent 29% ~= 2 blocks/CU despite static limits allowing 8.
// R17 change (isolated): LDS 18.4KB -> 10.1KB via union(lg | ushort list)
// + __launch_bounds__ min-waves hint — probe whether the residency cap is
// LDS-driven. Each block uses exactly one union member (one branch).
#define K1_SB 8
#define NTOPB (B / K1_SB)     // 256
#define KCH     4
#define KLEN    (NH / KCH)    // 128
#define SG      16
#define SCR_PAD 320

__global__ __launch_bounds__(320, 6) void k_gemms(const float* __restrict__ X,
                                                  const int* __restrict__ labels,
                                                  const float* __restrict__ Wt,
                                                  const float* __restrict__ bt,
                                                  const float* __restrict__ Wb,
                                                  float* __restrict__ scratch,
                                                  float* __restrict__ out) {
    __shared__ union {
        float lg[K1_SB][NC];                               // top branch: 10112 B
        struct {
            unsigned short list[B + SG];                   // blogits: 4128 B
            int cnt;
        } bl;
    } sh;                                                  // total: 10112 B
    const int tid = threadIdx.x;

    if (blockIdx.x < NTOPB) {
        // ----------------- k_top v3 body -----------------
        const int b0 = blockIdx.x * K1_SB;

        if (tid < NC) {
            float acc[K1_SB];
            #pragma unroll
            for (int s = 0; s < K1_SB; ++s) acc[s] = 0.f;
            const float* __restrict__ Xb = X + (size_t)b0 * NH;
            #pragma unroll 2
            for (int k = 0; k < NH; k += 4) {
                const float w0 = Wt[(k + 0) * NC + tid];
                const float w1 = Wt[(k + 1) * NC + tid];
                const float w2 = Wt[(k + 2) * NC + tid];
                const float w3 = Wt[(k + 3) * NC + tid];
                #pragma unroll
                for (int s = 0; s < K1_SB; ++s) {
                    const float4 xv = *(const float4*)&Xb[s * NH + k];  // uniform -> s_load
                    acc[s] += xv.x * w0 + xv.y * w1 + xv.z * w2 + xv.w * w3;
                }
            }
            const float bbv = bt[tid];
            #pragma unroll
            for (int s = 0; s < K1_SB; ++s) sh.lg[s][tid] = acc[s] + bbv;
        }
        __syncthreads();

        const int wave = tid >> 6, lane = tid & 63;
        float* __restrict__ top_probs = out + OFF_TOPP;
        float* __restrict__ top_indx  = out + OFF_TIDX;

        for (int s = wave; s < K1_SB; s += 5) {
            const int b = b0 + s;
            float m = -INFINITY; int mi = 0;
            for (int c = lane; c < NC; c += 64) {
                float v = sh.lg[s][c];
                if (v > m) { m = v; mi = c; }
            }
            for (int off = 32; off > 0; off >>= 1) {
                float om = __shfl_xor(m, off);
                int omi  = __shfl_xor(mi, off);
                if (om > m || (om == m && omi < mi)) { m = om; mi = omi; }
            }
            float sum = 0.f;
            for (int c = lane; c < NC; c += 64) sum += expf(sh.lg[s][c] - m);
            for (int off = 32; off > 0; off >>= 1) sum += __shfl_xor(sum, off);
            const float inv = 1.0f / sum;
            for (int c = lane; c < NC; c += 64)
                top_probs[(size_t)b * NC + c] = expf(sh.lg[s][c] - m) * inv;
            if (lane == 0) top_indx[b] = (float)mi;
        }
    } else {
        // ----------------- k_blogits body (KCH=4, nt weight loads) -----------------
        const int idx = blockIdx.x - NTOPB;
        const int c   = idx % NC;
        const int kc  = idx / NC;

        if (tid == 0) sh.bl.cnt = 0;
        __syncthreads();

        for (int i = tid; i < B; i += 320) {
            int lab = labels[i];
            if (lab / TPC == c) sh.bl.list[atomicAdd(&sh.bl.cnt, 1)] = (unsigned short)i;
        }
        __syncthreads();
        const int n = sh.bl.cnt;
        if (n == 0) return;
        if (tid < SG) sh.bl.list[n + tid] = sh.bl.list[0];   // pad: safe garbage samples
        __syncthreads();

        const float* __restrict__ Wc = Wb + (size_t)c * NH * TPC + (size_t)kc * KLEN * TPC;
        const int xoff = kc * KLEN;

        for (int start = 0; start < n; start += SG) {
            const int ns = min(SG, n - start);
            int sb[SG];
            #pragma unroll
            for (int s = 0; s < SG; ++s)
                sb[s] = __builtin_amdgcn_readfirstlane((int)sh.bl.list[start + s]) * NH + xoff;

            if (tid < TPC) {
                float acc[SG];
                #pragma unroll
                for (int s = 0; s < SG; ++s) acc[s] = 0.f;

                for (int k = 0; k < KLEN; k += 4) {
                    const float w0 = __builtin_nontemporal_load(&Wc[(size_t)(k + 0) * TPC + tid]);
                    const float w1 = __builtin_nontemporal_load(&Wc[(size_t)(k + 1) * TPC + tid]);
                    const float w2 = __builtin_nontemporal_load(&Wc[(size_t)(k + 2) * TPC + tid]);
                    const float w3 = __builtin_nontemporal_load(&Wc[(size_t)(k + 3) * TPC + tid]);
                    #pragma unroll
                    for (int s = 0; s < 8; ++s) {
                        const float4 xv = *(const float4*)&X[sb[s] + k];   // s_load
                        acc[s] += xv.x * w0 + xv.y * w1 + xv.z * w2 + xv.w * w3;
                    }
                    #pragma unroll
                    for (int s = 8; s < SG; ++s) {
                        const float4 xv = *(const float4*)&X[sb[s] + k];   // s_load
                        acc[s] += xv.x * w0 + xv.y * w1 + xv.z * w2 + xv.w * w3;
                    }
                }
                for (int s = 0; s < ns; ++s)
                    scratch[((size_t)sh.bl.list[start + s] * KCH + kc) * SCR_PAD + tid] = acc[s];
            }
        }
    }
}

// ------------- k_bfinal: reduce partials + bias, softmax, outputs -------------
__global__ __launch_bounds__(256) void k_bfinal(const int* __restrict__ labels,
                                                const float* __restrict__ bbias,
                                                const float* __restrict__ scratch,
                                                float* __restrict__ out) {
    const int tid  = threadIdx.x;
    const int lane = tid & 63;
    const int b    = blockIdx.x * 4 + (tid >> 6);

    const int lab = labels[b];
    const int c   = lab / TPC;
    const int pb  = lab - c * TPC;

    float lgv[5];
    #pragma unroll
    for (int i = 0; i < 5; ++i) {
        const int t = lane + 64 * i;
        float v = -INFINITY;
        if (t < TPC) {
            v = bbias[(size_t)c * TPC + t];
            #pragma unroll
            for (int kc = 0; kc < KCH; ++kc)
                v += scratch[((size_t)b * KCH + kc) * SCR_PAD + t];
        }
        lgv[i] = v;
    }

    float m = -INFINITY; int mi = 0;
    #pragma unroll
    for (int i = 0; i < 5; ++i) {
        const int t = lane + 64 * i;
        if (lgv[i] > m) { m = lgv[i]; mi = t; }
    }
    for (int off = 32; off > 0; off >>= 1) {
        float om = __shfl_xor(m, off);
        int omi  = __shfl_xor(mi, off);
        if (om > m || (om == m && omi < mi)) { m = om; mi = omi; }
    }

    float pv[5];
    float sum = 0.f;
    #pragma unroll
    for (int i = 0; i < 5; ++i) {
        const int t = lane + 64 * i;
        pv[i] = (t < TPC) ? expf(lgv[i] - m) : 0.f;
        sum += pv[i];
    }
    for (int off = 32; off > 0; off >>= 1) sum += __shfl_xor(sum, off);
    const float inv = 1.0f / sum;

    float* __restrict__ bot = out + OFF_BOTP + (size_t)b * TPC;
    float tsel = 0.f;
    #pragma unroll
    for (int i = 0; i < 5; ++i) {
        const int t = lane + 64 * i;
        if (t < TPC) {
            const float p = pv[i] * inv;
            bot[t] = p;
            if (t == pb) tsel = p;
        }
    }
    for (int off = 32; off > 0; off >>= 1) tsel += __shfl_xor(tsel, off);

    if (lane == 0) {
        out[OFF_TGT + b]  = out[OFF_TOPP + (size_t)b * NC + c] * tsel;
        out[OFF_BIDX + b] = (float)mi;
        out[OFF_RIDX + b] = out[OFF_TIDX + b] * (float)TPC + (float)mi;
    }
}

// ------------- k_preds v1 (accepted): 20 blocks/row scalar stream -------------
#define K3_THREADS 256
#define K3_ITERS   20
#define K3_BLOCKS_PER_ROW ((ROWLEN + K3_THREADS * K3_ITERS - 1) / (K3_THREADS * K3_ITERS))  // 20

__global__ __launch_bounds__(K3_THREADS) void k_preds(const float* __restrict__ out_ro,
                                                      float* __restrict__ preds) {
    __shared__ float tp[NC];
    __shared__ float bp[TPC];
    const int b = blockIdx.y;
    const int tid = threadIdx.x;

    const float* __restrict__ trow = out_ro + OFF_TOPP + (size_t)b * NC;
    const float* __restrict__ brow = out_ro + OFF_BOTP + (size_t)b * TPC;
    for (int i = tid; i < NC;  i += K3_THREADS) tp[i] = trow[i];
    for (int i = tid; i < TPC; i += K3_THREADS) bp[i] = brow[i];
    __syncthreads();

    int j = blockIdx.x * (K3_THREADS * K3_ITERS) + tid;
    int c = j / TPC;            // constant divisor -> magic-mul
    int t = j - c * TPC;
    float* __restrict__ row = preds + (size_t)b * ROWLEN;

    #pragma unroll
    for (int i = 0; i < K3_ITERS; ++i) {
        if (j < ROWLEN) row[j] = tp[c] * bp[t];
        j += K3_THREADS;
        t += K3_THREADS;
        if (t >= TPC) { t -= TPC; c++; }
    }
}

// ------------- k_loss: deterministic single-block reduce -------------
__global__ __launch_bounds__(256) void k_loss(const float* __restrict__ out_ro,
                                              float* __restrict__ out) {
    __shared__ float red[4];
    const int tid = threadIdx.x;
    const float* __restrict__ target = out_ro + OFF_TGT;
    float s = 0.f;
    for (int i = tid; i < B; i += 256) s += logf(target[i]);
    for (int off = 32; off > 0; off >>= 1) s += __shfl_xor(s, off);
    if ((tid & 63) == 0) red[tid >> 6] = s;
    __syncthreads();
    if (tid == 0) {
        float tot = red[0] + red[1] + red[2] + red[3];
        out[OFF_LOSS] = -tot / (float)B;
    }
}

extern "C" void kernel_launch(void* const* d_in, const int* in_sizes, int n_in,
                              void* d_out, int out_size, void* d_ws, size_t ws_size,
                              hipStream_t stream) {
    const float* X      = (const float*)d_in[0];
    const int*   labels = (const int*)d_in[1];
    // d_in[2] = ntokens_per_class (scalar, hardcoded as TPC)
    const float* Wt = (const float*)d_in[3];
    const float* bt = (const float*)d_in[4];
    const float* Wb = (const float*)d_in[5];
    const float* bb = (const float*)d_in[6];
    float* out = (float*)d_out;
    float* scratch = out + OFF_PREDS;   // preds region doubles as scratch,
                                        // fully overwritten by k_preds later

    k_gemms<<<dim3(NTOPB + NC * KCH), dim3(320), 0, stream>>>(X, labels, Wt, bt, Wb, scratch, out);
    k_bfinal<<<dim3(B / 4), dim3(256), 0, stream>>>(labels, bb, scratch, out);
    k_preds<<<dim3(K3_BLOCKS_PER_ROW, B), dim3(K3_THREADS), 0, stream>>>(out, out + OFF_PREDS);
    k_loss<<<dim3(1), dim3(256), 0, stream>>>(out, out);
}